// Round 1
// baseline (290.646 us; speedup 1.0000x reference)
//
#include <hip/hip_runtime.h>

// FWHT of 2^26 fp32 elements, decomposed into 3 passes over memory:
//   K1: bits 0..12  (contiguous lines of 8192 floats, LDS-resident, bits 0-1 in regs)
//   K2: bits 13..19 (stride 2^13, 128x32 LDS tile per block)
//   K3: bits 20..25 (stride 2^20, 64-point FWHT fully in registers)
// All stages commute, so this equals the reference's stride-(n/2..1) order.

#define EXP_TOTAL 26

// ---------------- K1: low 13 bits ----------------
__global__ __launch_bounds__(256) void fwht_low(const float* __restrict__ in,
                                                float* __restrict__ out) {
    __shared__ float lds[8192];
    const int t = threadIdx.x;
    const size_t base = (size_t)blockIdx.x * 8192;
    const float4* in4 = reinterpret_cast<const float4*>(in + base);
    float4* out4 = reinterpret_cast<float4*>(out + base);
    float4* lds4 = reinterpret_cast<float4*>(lds);

    // Load + butterfly bits 0,1 inside each float4 (register-only)
    #pragma unroll
    for (int k = 0; k < 8; ++k) {
        float4 v = in4[t + 256 * k];
        float a0 = v.x + v.y, a1 = v.x - v.y;
        float a2 = v.z + v.w, a3 = v.z - v.w;
        float4 w;
        w.x = a0 + a2; w.y = a1 + a3;
        w.z = a0 - a2; w.w = a1 - a3;
        lds4[t + 256 * k] = w;
    }
    __syncthreads();

    // Bits 2..12: quad-aligned butterflies in LDS. h4 = distance in float4 units.
    #pragma unroll
    for (int h4 = 1; h4 <= 1024; h4 <<= 1) {
        #pragma unroll
        for (int k = 0; k < 4; ++k) {
            int q = t + 256 * k;                       // quad-pair id, 0..1023
            int j = ((q & ~(h4 - 1)) << 1) | (q & (h4 - 1));
            float4 a = lds4[j];
            float4 b = lds4[j + h4];
            float4 s, d;
            s.x = a.x + b.x; s.y = a.y + b.y; s.z = a.z + b.z; s.w = a.w + b.w;
            d.x = a.x - b.x; d.y = a.y - b.y; d.z = a.z - b.z; d.w = a.w - b.w;
            lds4[j] = s;
            lds4[j + h4] = d;
        }
        __syncthreads();
    }

    #pragma unroll
    for (int k = 0; k < 8; ++k)
        out4[t + 256 * k] = lds4[t + 256 * k];
}

// ---------------- K2: mid 7 bits (13..19), row stride 2^13 ----------------
__global__ __launch_bounds__(256) void fwht_mid(float* __restrict__ data) {
    __shared__ float tile[128][32];
    const int t = threadIdx.x;
    const int c = t & 31;          // column within tile (bits 0..4 of low index)
    const int r0 = t >> 5;         // 0..7
    const int colTile = blockIdx.x & 255;   // bits 5..12
    const int high = blockIdx.x >> 8;       // bits 20..25 (64 groups)
    const size_t base = ((size_t)high << 20) + (size_t)colTile * 32 + c;

    #pragma unroll
    for (int k = 0; k < 16; ++k) {
        int r = r0 + 8 * k;
        tile[r][c] = data[base + ((size_t)r << 13)];
    }
    __syncthreads();

    #pragma unroll
    for (int h = 1; h <= 64; h <<= 1) {
        #pragma unroll
        for (int k = 0; k < 8; ++k) {
            int pr = r0 + 8 * k;                       // pair id 0..63
            int r = ((pr & ~(h - 1)) << 1) | (pr & (h - 1));
            float a = tile[r][c];
            float b = tile[r + h][c];
            tile[r][c] = a + b;
            tile[r + h][c] = a - b;
        }
        __syncthreads();
    }

    #pragma unroll
    for (int k = 0; k < 16; ++k) {
        int r = r0 + 8 * k;
        data[base + ((size_t)r << 13)] = tile[r][c];
    }
}

// ---------------- K3: high 6 bits (20..25), row stride 2^20, registers ----------------
__global__ __launch_bounds__(256) void fwht_high(float* __restrict__ data) {
    const size_t g = (size_t)blockIdx.x * 256 + threadIdx.x;   // 0 .. 2^20-1
    float v[64];
    #pragma unroll
    for (int r = 0; r < 64; ++r)
        v[r] = data[g + ((size_t)r << 20)];

    #pragma unroll
    for (int h = 1; h < 64; h <<= 1) {
        #pragma unroll
        for (int j = 0; j < 64; j += 2 * h) {
            #pragma unroll
            for (int k = 0; k < h; ++k) {
                float a = v[j + k];
                float b = v[j + k + h];
                v[j + k] = a + b;
                v[j + k + h] = a - b;
            }
        }
    }

    #pragma unroll
    for (int r = 0; r < 64; ++r)
        data[g + ((size_t)r << 20)] = v[r];
}

extern "C" void kernel_launch(void* const* d_in, const int* in_sizes, int n_in,
                              void* d_out, int out_size, void* d_ws, size_t ws_size,
                              hipStream_t stream) {
    const float* x = (const float*)d_in[0];
    float* out = (float*)d_out;
    // n = 2^26 fixed by the reference.
    fwht_low<<<8192, 256, 0, stream>>>(x, out);     // bits 0..12, in -> out
    fwht_mid<<<16384, 256, 0, stream>>>(out);       // bits 13..19, in place
    fwht_high<<<4096, 256, 0, stream>>>(out);       // bits 20..25, in place
}